// Round 3
// baseline (1024.769 us; speedup 1.0000x reference)
//
#include <hip/hip_runtime.h>
#include <hip/hip_bf16.h>
#include <cstddef>

#define N_NODES 100000
#define N_EDGES 1600000
#define IN_C 512
#define HID_C 128
#define OUT_C 40
#define NB_SCAN 391  // ceil((N_NODES+1)/256)

typedef short bf16x8 __attribute__((ext_vector_type(8)));
typedef float f32x4 __attribute__((ext_vector_type(4)));

__device__ __forceinline__ float bf2f(unsigned short u) {
    union { unsigned int i; float f; } v; v.i = ((unsigned int)u) << 16; return v.f;
}
__device__ __forceinline__ unsigned short f2bf(float f) {
    union { float f; unsigned int i; } v; v.f = f;
    unsigned int x = v.i;
    return (unsigned short)((x + 0x7FFFu + ((x >> 16) & 1u)) >> 16);  // RNE
}

// ---- dtype detection -------------------------------------------------------
// flags[0]: 1 if float tensors are bf16, 0 if fp32.
// flags[1]: 1 if edge_index is int64, 0 if int32.
__global__ void k_detect(const unsigned int* __restrict__ xbits,
                         const int* __restrict__ ei32, int* __restrict__ flags) {
    if (threadIdx.x == 0 && blockIdx.x == 0) {
        // fp32 N(0,1): exponent field in ~[100,135]. bf16 pair reinterpreted as
        // fp32: exponent comes from a bf16's low exp/mantissa bits -> >=200 or <=3.
        int inrange = 0;
        for (int i = 0; i < 64; i++) {
            unsigned int b = xbits[i * 33 + 1];
            int e = (int)((b >> 23) & 0xFFu);
            if (e >= 90 && e <= 160) inrange++;
        }
        flags[0] = (inrange >= 32) ? 0 : 1;
        // int64 indices < 2^31: odd int32 words (high halves) are all zero.
        int zeros = 0;
        for (int i = 0; i < 8; i++) if (ei32[2 * i + 1] == 0) zeros++;
        flags[1] = (zeros == 8) ? 1 : 0;
    }
}

__device__ __forceinline__ int load_src(const int* ei, int mi, int e) {
    return mi ? ei[2 * e] : ei[e];
}
__device__ __forceinline__ int load_dst(const int* ei, int mi, int e) {
    return mi ? ei[2 * (N_EDGES + e)] : ei[N_EDGES + e];
}

// ---- weight/bias normalization: W -> bf16, b -> f32 ------------------------
#define NW_TOTAL (IN_C * HID_C + HID_C * OUT_C + HID_C + OUT_C)
__global__ void k_norm_w(const void* __restrict__ W0, const void* __restrict__ W1,
                         const void* __restrict__ b0, const void* __restrict__ b1,
                         const int* __restrict__ flags,
                         unsigned short* __restrict__ w0n, unsigned short* __restrict__ w1n,
                         float* __restrict__ b0n, float* __restrict__ b1n) {
    int mf = flags[0];
    int i = blockIdx.x * 256 + threadIdx.x;
    if (i >= NW_TOTAL) return;
    if (i < IN_C * HID_C) {
        w0n[i] = mf ? ((const unsigned short*)W0)[i] : f2bf(((const float*)W0)[i]);
    } else if (i < IN_C * HID_C + HID_C * OUT_C) {
        int j = i - IN_C * HID_C;
        w1n[j] = mf ? ((const unsigned short*)W1)[j] : f2bf(((const float*)W1)[j]);
    } else if (i < IN_C * HID_C + HID_C * OUT_C + HID_C) {
        int j = i - IN_C * HID_C - HID_C * OUT_C;
        b0n[j] = mf ? bf2f(((const unsigned short*)b0)[j]) : ((const float*)b0)[j];
    } else {
        int j = i - IN_C * HID_C - HID_C * OUT_C - HID_C;
        b1n[j] = mf ? bf2f(((const unsigned short*)b1)[j]) : ((const float*)b1)[j];
    }
}

// ---- CSR build -------------------------------------------------------------

__global__ void k_count(const int* __restrict__ ei, const int* __restrict__ flags,
                        int* __restrict__ cnt) {
    int e = blockIdx.x * 256 + threadIdx.x;
    if (e < N_EDGES) atomicAdd(&cnt[load_dst(ei, flags[1], e)], 1);
}

__global__ void k_scan_a(const int* __restrict__ cnt, int* __restrict__ bsum) {
    __shared__ int sm[256];
    int i = blockIdx.x * 256 + threadIdx.x;
    int v = (i < N_NODES) ? cnt[i] : 0;
    sm[threadIdx.x] = v; __syncthreads();
    for (int s = 128; s > 0; s >>= 1) {
        if (threadIdx.x < s) sm[threadIdx.x] += sm[threadIdx.x + s];
        __syncthreads();
    }
    if (threadIdx.x == 0) bsum[blockIdx.x] = sm[0];
}

__global__ void k_scan_b(const int* __restrict__ bsum, int* __restrict__ boff) {
    __shared__ int sm[512];
    int t = threadIdx.x;
    int v = (t < NB_SCAN) ? bsum[t] : 0;
    sm[t] = v; __syncthreads();
    for (int off = 1; off < 512; off <<= 1) {
        int add = (t >= off) ? sm[t - off] : 0;
        __syncthreads();
        sm[t] += add;
        __syncthreads();
    }
    boff[t] = sm[t] - v;  // exclusive
}

// cnt and cursor alias the same buffer: each thread reads its own cnt[i] before
// overwriting it (1:1 mapping, safe).
__global__ void k_scan_c(const int* cnt, const int* __restrict__ boff,
                         int* __restrict__ rowptr, int* cursor, float* __restrict__ dinv) {
    __shared__ int sm[256];
    int t = threadIdx.x;
    int i = blockIdx.x * 256 + t;
    int v = (i < N_NODES) ? cnt[i] : 0;
    sm[t] = v; __syncthreads();
    for (int off = 1; off < 256; off <<= 1) {
        int add = (t >= off) ? sm[t - off] : 0;
        __syncthreads();
        sm[t] += add;
        __syncthreads();
    }
    int p = boff[blockIdx.x] + sm[t] - v;
    if (i < N_NODES) {
        rowptr[i] = p;
        cursor[i] = p;
        float d = (float)v;
        if (d < 1.0f) d = 1.0f;
        dinv[i] = rsqrtf(d);
    } else if (i == N_NODES) {
        rowptr[N_NODES] = p;  // == N_EDGES
    }
}

__global__ void k_fill(const int* __restrict__ ei, const int* __restrict__ flags,
                       int* cursor, int* __restrict__ col) {
    int e = blockIdx.x * 256 + threadIdx.x;
    if (e < N_EDGES) {
        int mi = flags[1];
        int d = load_dst(ei, mi, e);
        int p = atomicAdd(&cursor[d], 1);
        col[p] = load_src(ei, mi, e);
    }
}

// ---- GEMM1: H1[N,128] = x[N,512] @ W0[128,512]^T  (bf16 MFMA, bf16 out) ----
// A frag: A[m=lane&15][k=k0+(lane>>4)*8+j]  (16B contiguous per lane)
// B frag: B[n=lane&15][k=...]  (W0n row-major [c][k], same pattern)
// C/D:    chan = lane&15, node = (lane>>4)*4 + reg   (m89/m91-verified mapping)
template <int MF>
__device__ __forceinline__ void gemm1_body(const void* __restrict__ x,
                                           const unsigned short* __restrict__ w0n,
                                           unsigned short* __restrict__ h1,
                                           int wave, int lane) {
    int r16 = lane & 15;
    int quad = lane >> 4;
    int node_base = wave * 16;

    f32x4 acc[8];
#pragma unroll
    for (int c = 0; c < 8; c++) acc[c] = (f32x4){0.f, 0.f, 0.f, 0.f};

    const unsigned short* wrow = w0n + (size_t)r16 * IN_C + quad * 8;
    const unsigned short* xrow_h = (const unsigned short*)x + (size_t)(node_base + r16) * IN_C + quad * 8;
    const float* xrow_f = (const float*)x + (size_t)(node_base + r16) * IN_C + quad * 8;

    for (int k0 = 0; k0 < IN_C; k0 += 32) {
        bf16x8 a;
        if (MF) {
            a = *reinterpret_cast<const bf16x8*>(xrow_h + k0);
        } else {
            float4 f0 = *reinterpret_cast<const float4*>(xrow_f + k0);
            float4 f1 = *reinterpret_cast<const float4*>(xrow_f + k0 + 4);
            a = (bf16x8){(short)f2bf(f0.x), (short)f2bf(f0.y), (short)f2bf(f0.z), (short)f2bf(f0.w),
                         (short)f2bf(f1.x), (short)f2bf(f1.y), (short)f2bf(f1.z), (short)f2bf(f1.w)};
        }
#pragma unroll
        for (int ct = 0; ct < 8; ct++) {
            bf16x8 b = *reinterpret_cast<const bf16x8*>(wrow + (size_t)ct * 16 * IN_C + k0);
            acc[ct] = __builtin_amdgcn_mfma_f32_16x16x32_bf16(a, b, acc[ct], 0, 0, 0);
        }
    }

#pragma unroll
    for (int ct = 0; ct < 8; ct++) {
#pragma unroll
        for (int r = 0; r < 4; r++) {
            h1[(size_t)(node_base + quad * 4 + r) * HID_C + ct * 16 + r16] = f2bf(acc[ct][r]);
        }
    }
}

__global__ __launch_bounds__(256) void k_gemm1(const void* __restrict__ x,
                                               const unsigned short* __restrict__ w0n,
                                               const int* __restrict__ flags,
                                               unsigned short* __restrict__ h1) {
    int wave = (blockIdx.x * 256 + (int)threadIdx.x) >> 6;
    if (wave >= N_NODES / 16) return;
    int lane = threadIdx.x & 63;
    if (flags[0]) gemm1_body<1>(x, w0n, h1, wave, lane);
    else          gemm1_body<0>(x, w0n, h1, wave, lane);
}

// ---- Aggregation layer 1 (+bias+relu), dst-centric, no atomics -------------
__global__ void k_agg1(const int* __restrict__ rowptr, const int* __restrict__ col,
                       const float* __restrict__ dinv, const unsigned short* __restrict__ h1,
                       const float* __restrict__ b0n, unsigned short* __restrict__ h2) {
    int d = blockIdx.x;
    int c = threadIdx.x;  // 0..127
    int beg = rowptr[d], end = rowptr[d + 1];
    float acc = 0.f;
    for (int j = beg; j < end; j++) {
        int s = col[j];
        acc += dinv[s] * bf2f(h1[(size_t)s * HID_C + c]);
    }
    float out = acc * dinv[d] + b0n[c];
    h2[(size_t)d * HID_C + c] = f2bf(out > 0.f ? out : 0.f);
}

// ---- GEMM2: P2[N,40] = H2[N,128] @ W1[40,128]^T (small; VALU, f32 out) -----
__global__ void k_gemm2(const unsigned short* __restrict__ h2, const unsigned short* __restrict__ w1n,
                        float* __restrict__ p2) {
    int lane = threadIdx.x;  // 0..63 (c = lane, <40 active)
    int n = blockIdx.x * 4 + threadIdx.y;
    if (n >= N_NODES || lane >= OUT_C) return;
    const ushort4* hv = reinterpret_cast<const ushort4*>(h2 + (size_t)n * HID_C);
    const ushort4* wv = reinterpret_cast<const ushort4*>(w1n + (size_t)lane * HID_C);
    float acc = 0.f;
#pragma unroll
    for (int k = 0; k < HID_C / 4; k++) {
        ushort4 h = hv[k];
        ushort4 w = wv[k];
        acc += bf2f(h.x) * bf2f(w.x) + bf2f(h.y) * bf2f(w.y)
             + bf2f(h.z) * bf2f(w.z) + bf2f(h.w) * bf2f(w.w);
    }
    p2[(size_t)n * OUT_C + lane] = acc;
}

// ---- Aggregation layer 2 (+bias), output dtype per detected mode -----------
__global__ void k_agg2(const int* __restrict__ rowptr, const int* __restrict__ col,
                       const float* __restrict__ dinv, const float* __restrict__ p2,
                       const float* __restrict__ b1n, const int* __restrict__ flags,
                       void* __restrict__ out) {
    int d = blockIdx.x;
    int c = threadIdx.x;  // 0..63
    if (c >= OUT_C) return;
    int beg = rowptr[d], end = rowptr[d + 1];
    float acc = 0.f;
    for (int j = beg; j < end; j++) {
        int s = col[j];
        acc += dinv[s] * p2[(size_t)s * OUT_C + c];
    }
    float v = acc * dinv[d] + b1n[c];
    size_t idx = (size_t)d * OUT_C + c;
    if (flags[0]) ((unsigned short*)out)[idx] = f2bf(v);
    else          ((float*)out)[idx] = v;
}

extern "C" void kernel_launch(void* const* d_in, const int* in_sizes, int n_in,
                              void* d_out, int out_size, void* d_ws, size_t ws_size,
                              hipStream_t stream) {
    const void* x  = d_in[0];
    const int* ei  = (const int*)d_in[1];
    const void* W0 = d_in[2];
    const void* b0 = d_in[3];
    const void* W1 = d_in[4];
    const void* b1 = d_in[5];

    char* ws = (char*)d_ws;
    size_t off = 0;
    auto alloc = [&](size_t bytes) {
        char* p = ws + off;
        off += (bytes + 511) & ~(size_t)511;
        return p;
    };
    // Total footprint ~59 MB.
    int*   flags  = (int*)  alloc(sizeof(int) * 2);
    int*   cnt    = (int*)  alloc(sizeof(int) * N_NODES);        // reused as cursor
    int*   rowptr = (int*)  alloc(sizeof(int) * (N_NODES + 1));
    float* dinv   = (float*)alloc(sizeof(float) * N_NODES);
    int*   col    = (int*)  alloc(sizeof(int) * N_EDGES);
    int*   bsum   = (int*)  alloc(sizeof(int) * 512);
    int*   boff   = (int*)  alloc(sizeof(int) * 512);
    unsigned short* w0n = (unsigned short*)alloc(sizeof(unsigned short) * IN_C * HID_C);
    unsigned short* w1n = (unsigned short*)alloc(sizeof(unsigned short) * HID_C * OUT_C);
    float* b0n = (float*)alloc(sizeof(float) * HID_C);
    float* b1n = (float*)alloc(sizeof(float) * OUT_C);
    unsigned short* h1 = (unsigned short*)alloc(sizeof(unsigned short) * (size_t)N_NODES * HID_C);
    unsigned short* h2 = (unsigned short*)alloc(sizeof(unsigned short) * (size_t)N_NODES * HID_C);
    float* p2 = (float*)h1;  // h1 dead after k_agg1; 16 MB fits inside h1's 25.6 MB

    k_detect<<<1, 64, 0, stream>>>((const unsigned int*)x, ei, flags);
    k_norm_w<<<(NW_TOTAL + 255) / 256, 256, 0, stream>>>(W0, W1, b0, b1, flags, w0n, w1n, b0n, b1n);

    hipMemsetAsync(cnt, 0, sizeof(int) * N_NODES, stream);
    k_count<<<(N_EDGES + 255) / 256, 256, 0, stream>>>(ei, flags, cnt);
    k_scan_a<<<NB_SCAN, 256, 0, stream>>>(cnt, bsum);
    k_scan_b<<<1, 512, 0, stream>>>(bsum, boff);
    k_scan_c<<<NB_SCAN, 256, 0, stream>>>(cnt, boff, rowptr, cnt, dinv);
    k_fill<<<(N_EDGES + 255) / 256, 256, 0, stream>>>(ei, flags, cnt, col);

    k_gemm1<<<(N_NODES / 16 + 3) / 4, 256, 0, stream>>>(x, w0n, flags, h1);
    k_agg1<<<N_NODES, 128, 0, stream>>>(rowptr, col, dinv, h1, b0n, h2);
    dim3 b2(64, 4);
    k_gemm2<<<(N_NODES + 3) / 4, b2, 0, stream>>>(h2, w1n, p2);
    k_agg2<<<N_NODES, 64, 0, stream>>>(rowptr, col, dinv, p2, b1n, flags, d_out);
}

// Round 4
// 762.576 us; speedup vs baseline: 1.3438x; 1.3438x over previous
//
#include <hip/hip_runtime.h>
#include <hip/hip_bf16.h>
#include <cstddef>

#define N_NODES 100000
#define N_EDGES 1600000
#define IN_C 512
#define HID_C 128
#define OUT_C 40
#define OUT_CP 48   // padded col count for MFMA (3 x 16)
#define NB_SCAN 391  // ceil((N_NODES+1)/256)

typedef short bf16x8 __attribute__((ext_vector_type(8)));
typedef float f32x4 __attribute__((ext_vector_type(4)));

__device__ __forceinline__ float bf2f(unsigned short u) {
    union { unsigned int i; float f; } v; v.i = ((unsigned int)u) << 16; return v.f;
}
__device__ __forceinline__ float bf2f_lo(unsigned int u) {
    union { unsigned int i; float f; } v; v.i = u << 16; return v.f;
}
__device__ __forceinline__ float bf2f_hi(unsigned int u) {
    union { unsigned int i; float f; } v; v.i = u & 0xFFFF0000u; return v.f;
}
__device__ __forceinline__ unsigned short f2bf(float f) {
    union { float f; unsigned int i; } v; v.f = f;
    unsigned int x = v.i;
    return (unsigned short)((x + 0x7FFFu + ((x >> 16) & 1u)) >> 16);  // RNE
}

// ---- dtype detection -------------------------------------------------------
// flags[0]: 1 if float tensors are bf16, 0 if fp32.  flags[1]: 1 if edge_index int64.
__global__ void k_detect(const unsigned int* __restrict__ xbits,
                         const int* __restrict__ ei32, int* __restrict__ flags) {
    if (threadIdx.x == 0 && blockIdx.x == 0) {
        int inrange = 0;
        for (int i = 0; i < 64; i++) {
            unsigned int b = xbits[i * 33 + 1];
            int e = (int)((b >> 23) & 0xFFu);
            if (e >= 90 && e <= 160) inrange++;
        }
        flags[0] = (inrange >= 32) ? 0 : 1;
        int zeros = 0;
        for (int i = 0; i < 8; i++) if (ei32[2 * i + 1] == 0) zeros++;
        flags[1] = (zeros == 8) ? 1 : 0;
    }
}

__device__ __forceinline__ int load_src(const int* ei, int mi, int e) {
    return mi ? ei[2 * e] : ei[e];
}
__device__ __forceinline__ int load_dst(const int* ei, int mi, int e) {
    return mi ? ei[2 * (N_EDGES + e)] : ei[N_EDGES + e];
}

// ---- weight/bias normalization: W -> bf16 (W1 zero-padded to 48 rows) ------
#define NW_TOTAL (IN_C * HID_C + HID_C * OUT_C + HID_C + OUT_C)
__global__ void k_norm_w(const void* __restrict__ W0, const void* __restrict__ W1,
                         const void* __restrict__ b0, const void* __restrict__ b1,
                         const int* __restrict__ flags,
                         unsigned short* __restrict__ w0n, unsigned short* __restrict__ w1n,
                         float* __restrict__ b0n, float* __restrict__ b1n) {
    int mf = flags[0];
    int i = blockIdx.x * 256 + threadIdx.x;
    if (i >= NW_TOTAL) return;
    if (i < IN_C * HID_C) {
        w0n[i] = mf ? ((const unsigned short*)W0)[i] : f2bf(((const float*)W0)[i]);
    } else if (i < IN_C * HID_C + HID_C * OUT_C) {
        int j = i - IN_C * HID_C;
        w1n[j] = mf ? ((const unsigned short*)W1)[j] : f2bf(((const float*)W1)[j]);
    } else if (i < IN_C * HID_C + HID_C * OUT_C + HID_C) {
        int j = i - IN_C * HID_C - HID_C * OUT_C;
        b0n[j] = mf ? bf2f(((const unsigned short*)b0)[j]) : ((const float*)b0)[j];
    } else {
        int j = i - IN_C * HID_C - HID_C * OUT_C - HID_C;
        b1n[j] = mf ? bf2f(((const unsigned short*)b1)[j]) : ((const float*)b1)[j];
    }
}

// ---- CSR build -------------------------------------------------------------

__global__ void k_count(const int* __restrict__ ei, const int* __restrict__ flags,
                        int* __restrict__ cnt) {
    int e = blockIdx.x * 256 + threadIdx.x;
    if (e < N_EDGES) atomicAdd(&cnt[load_dst(ei, flags[1], e)], 1);
}

__global__ void k_scan_a(const int* __restrict__ cnt, int* __restrict__ bsum) {
    __shared__ int sm[256];
    int i = blockIdx.x * 256 + threadIdx.x;
    int v = (i < N_NODES) ? cnt[i] : 0;
    sm[threadIdx.x] = v; __syncthreads();
    for (int s = 128; s > 0; s >>= 1) {
        if (threadIdx.x < s) sm[threadIdx.x] += sm[threadIdx.x + s];
        __syncthreads();
    }
    if (threadIdx.x == 0) bsum[blockIdx.x] = sm[0];
}

__global__ void k_scan_b(const int* __restrict__ bsum, int* __restrict__ boff) {
    __shared__ int sm[512];
    int t = threadIdx.x;
    int v = (t < NB_SCAN) ? bsum[t] : 0;
    sm[t] = v; __syncthreads();
    for (int off = 1; off < 512; off <<= 1) {
        int add = (t >= off) ? sm[t - off] : 0;
        __syncthreads();
        sm[t] += add;
        __syncthreads();
    }
    boff[t] = sm[t] - v;  // exclusive
}

__global__ void k_scan_c(const int* cnt, const int* __restrict__ boff,
                         int* __restrict__ rowptr, int* cursor, float* __restrict__ dinv) {
    __shared__ int sm[256];
    int t = threadIdx.x;
    int i = blockIdx.x * 256 + t;
    int v = (i < N_NODES) ? cnt[i] : 0;
    sm[t] = v; __syncthreads();
    for (int off = 1; off < 256; off <<= 1) {
        int add = (t >= off) ? sm[t - off] : 0;
        __syncthreads();
        sm[t] += add;
        __syncthreads();
    }
    int p = boff[blockIdx.x] + sm[t] - v;
    if (i < N_NODES) {
        rowptr[i] = p;
        cursor[i] = p;
        float d = (float)v;
        if (d < 1.0f) d = 1.0f;
        dinv[i] = rsqrtf(d);
    } else if (i == N_NODES) {
        rowptr[N_NODES] = p;
    }
}

__global__ void k_fill(const int* __restrict__ ei, const int* __restrict__ flags,
                       int* cursor, int* __restrict__ col) {
    int e = blockIdx.x * 256 + threadIdx.x;
    if (e < N_EDGES) {
        int mi = flags[1];
        int d = load_dst(ei, mi, e);
        int p = atomicAdd(&cursor[d], 1);
        col[p] = load_src(ei, mi, e);
    }
}

// ---- GEMM1: H1[N,128] = x[N,512] @ W0[128,512]^T  (bf16 MFMA, bf16 out) ----
template <int MF>
__device__ __forceinline__ void gemm1_body(const void* __restrict__ x,
                                           const unsigned short* __restrict__ w0n,
                                           unsigned short* __restrict__ h1,
                                           int wave, int lane) {
    int r16 = lane & 15;
    int quad = lane >> 4;
    int node_base = wave * 16;

    f32x4 acc[8];
#pragma unroll
    for (int c = 0; c < 8; c++) acc[c] = (f32x4){0.f, 0.f, 0.f, 0.f};

    const unsigned short* wrow = w0n + (size_t)r16 * IN_C + quad * 8;
    const unsigned short* xrow_h = (const unsigned short*)x + (size_t)(node_base + r16) * IN_C + quad * 8;
    const float* xrow_f = (const float*)x + (size_t)(node_base + r16) * IN_C + quad * 8;

    for (int k0 = 0; k0 < IN_C; k0 += 32) {
        bf16x8 a;
        if (MF) {
            a = *reinterpret_cast<const bf16x8*>(xrow_h + k0);
        } else {
            float4 f0 = *reinterpret_cast<const float4*>(xrow_f + k0);
            float4 f1 = *reinterpret_cast<const float4*>(xrow_f + k0 + 4);
            a = (bf16x8){(short)f2bf(f0.x), (short)f2bf(f0.y), (short)f2bf(f0.z), (short)f2bf(f0.w),
                         (short)f2bf(f1.x), (short)f2bf(f1.y), (short)f2bf(f1.z), (short)f2bf(f1.w)};
        }
#pragma unroll
        for (int ct = 0; ct < 8; ct++) {
            bf16x8 b = *reinterpret_cast<const bf16x8*>(wrow + (size_t)ct * 16 * IN_C + k0);
            acc[ct] = __builtin_amdgcn_mfma_f32_16x16x32_bf16(a, b, acc[ct], 0, 0, 0);
        }
    }

#pragma unroll
    for (int ct = 0; ct < 8; ct++) {
#pragma unroll
        for (int r = 0; r < 4; r++) {
            h1[(size_t)(node_base + quad * 4 + r) * HID_C + ct * 16 + r16] = f2bf(acc[ct][r]);
        }
    }
}

__global__ __launch_bounds__(256) void k_gemm1(const void* __restrict__ x,
                                               const unsigned short* __restrict__ w0n,
                                               const int* __restrict__ flags,
                                               unsigned short* __restrict__ h1) {
    int wave = (blockIdx.x * 256 + (int)threadIdx.x) >> 6;
    if (wave >= N_NODES / 16) return;
    int lane = threadIdx.x & 63;
    if (flags[0]) gemm1_body<1>(x, w0n, h1, wave, lane);
    else          gemm1_body<0>(x, w0n, h1, wave, lane);
}

// ---- Agg layer 1 (+bias+relu): one wave per node, uint(2xbf16)/lane, x4 ILP
__global__ __launch_bounds__(256) void k_agg1(const int* __restrict__ rowptr,
                                              const int* __restrict__ col,
                                              const float* __restrict__ dinv,
                                              const unsigned int* __restrict__ h1v,
                                              const float* __restrict__ b0n,
                                              unsigned int* __restrict__ h2v) {
    int w = threadIdx.x >> 6;
    int lane = threadIdx.x & 63;
    int d = blockIdx.x * 4 + w;
    if (d >= N_NODES) return;
    int beg = rowptr[d], end = rowptr[d + 1];
    float a0 = 0.f, a1 = 0.f;
    int j = beg;
    for (; j + 4 <= end; j += 4) {
        int s0 = col[j], s1 = col[j + 1], s2 = col[j + 2], s3 = col[j + 3];
        float w0 = dinv[s0], w1 = dinv[s1], w2 = dinv[s2], w3 = dinv[s3];
        unsigned int r0 = h1v[(size_t)s0 * 64 + lane];
        unsigned int r1 = h1v[(size_t)s1 * 64 + lane];
        unsigned int r2 = h1v[(size_t)s2 * 64 + lane];
        unsigned int r3 = h1v[(size_t)s3 * 64 + lane];
        a0 += w0 * bf2f_lo(r0) + w1 * bf2f_lo(r1) + w2 * bf2f_lo(r2) + w3 * bf2f_lo(r3);
        a1 += w0 * bf2f_hi(r0) + w1 * bf2f_hi(r1) + w2 * bf2f_hi(r2) + w3 * bf2f_hi(r3);
    }
    for (; j < end; j++) {
        int s = col[j];
        float wj = dinv[s];
        unsigned int r = h1v[(size_t)s * 64 + lane];
        a0 += wj * bf2f_lo(r);
        a1 += wj * bf2f_hi(r);
    }
    float dv = dinv[d];
    float o0 = a0 * dv + b0n[2 * lane];
    float o1 = a1 * dv + b0n[2 * lane + 1];
    o0 = o0 > 0.f ? o0 : 0.f;
    o1 = o1 > 0.f ? o1 : 0.f;
    h2v[(size_t)d * 64 + lane] = (unsigned int)f2bf(o0) | ((unsigned int)f2bf(o1) << 16);
}

// ---- GEMM2 (MFMA): P2[N,40] = H2[N,128] @ W1p[48,128]^T --------------------
__global__ __launch_bounds__(256) void k_gemm2(const unsigned short* __restrict__ h2,
                                               const unsigned short* __restrict__ w1p,
                                               float* __restrict__ p2) {
    int wave = (blockIdx.x * 256 + (int)threadIdx.x) >> 6;
    if (wave >= N_NODES / 16) return;
    int lane = threadIdx.x & 63;
    int r16 = lane & 15;
    int quad = lane >> 4;
    int node_base = wave * 16;

    f32x4 acc[3];
#pragma unroll
    for (int c = 0; c < 3; c++) acc[c] = (f32x4){0.f, 0.f, 0.f, 0.f};

    const unsigned short* arow = h2 + (size_t)(node_base + r16) * HID_C + quad * 8;
    const unsigned short* brow = w1p + (size_t)r16 * HID_C + quad * 8;

#pragma unroll
    for (int k0 = 0; k0 < HID_C; k0 += 32) {
        bf16x8 a = *reinterpret_cast<const bf16x8*>(arow + k0);
#pragma unroll
        for (int ct = 0; ct < 3; ct++) {
            bf16x8 b = *reinterpret_cast<const bf16x8*>(brow + (size_t)ct * 16 * HID_C + k0);
            acc[ct] = __builtin_amdgcn_mfma_f32_16x16x32_bf16(a, b, acc[ct], 0, 0, 0);
        }
    }

#pragma unroll
    for (int ct = 0; ct < 3; ct++) {
        int chan = ct * 16 + r16;
        if (chan < OUT_C) {
#pragma unroll
            for (int r = 0; r < 4; r++) {
                p2[(size_t)(node_base + quad * 4 + r) * OUT_C + chan] = acc[ct][r];
            }
        }
    }
}

// ---- Agg layer 2 (+bias): one wave per node, lanes 0..39, x4 ILP -----------
__global__ __launch_bounds__(256) void k_agg2(const int* __restrict__ rowptr,
                                              const int* __restrict__ col,
                                              const float* __restrict__ dinv,
                                              const float* __restrict__ p2,
                                              const float* __restrict__ b1n,
                                              const int* __restrict__ flags,
                                              void* __restrict__ out) {
    int w = threadIdx.x >> 6;
    int lane = threadIdx.x & 63;
    int d = blockIdx.x * 4 + w;
    if (d >= N_NODES || lane >= OUT_C) return;
    int beg = rowptr[d], end = rowptr[d + 1];
    float acc = 0.f;
    int j = beg;
    for (; j + 4 <= end; j += 4) {
        int s0 = col[j], s1 = col[j + 1], s2 = col[j + 2], s3 = col[j + 3];
        float w0 = dinv[s0], w1 = dinv[s1], w2 = dinv[s2], w3 = dinv[s3];
        float r0 = p2[(size_t)s0 * OUT_C + lane];
        float r1 = p2[(size_t)s1 * OUT_C + lane];
        float r2 = p2[(size_t)s2 * OUT_C + lane];
        float r3 = p2[(size_t)s3 * OUT_C + lane];
        acc += w0 * r0 + w1 * r1 + w2 * r2 + w3 * r3;
    }
    for (; j < end; j++) {
        int s = col[j];
        acc += dinv[s] * p2[(size_t)s * OUT_C + lane];
    }
    float v = acc * dinv[d] + b1n[lane];
    size_t idx = (size_t)d * OUT_C + lane;
    if (flags[0]) ((unsigned short*)out)[idx] = f2bf(v);
    else          ((float*)out)[idx] = v;
}

extern "C" void kernel_launch(void* const* d_in, const int* in_sizes, int n_in,
                              void* d_out, int out_size, void* d_ws, size_t ws_size,
                              hipStream_t stream) {
    const void* x  = d_in[0];
    const int* ei  = (const int*)d_in[1];
    const void* W0 = d_in[2];
    const void* b0 = d_in[3];
    const void* W1 = d_in[4];
    const void* b1 = d_in[5];

    char* ws = (char*)d_ws;
    size_t off = 0;
    auto alloc = [&](size_t bytes) {
        char* p = ws + off;
        off += (bytes + 511) & ~(size_t)511;
        return p;
    };
    // Total footprint ~59 MB.
    int*   flags  = (int*)  alloc(sizeof(int) * 2);
    int*   cnt    = (int*)  alloc(sizeof(int) * N_NODES);        // reused as cursor
    int*   rowptr = (int*)  alloc(sizeof(int) * (N_NODES + 1));
    float* dinv   = (float*)alloc(sizeof(float) * N_NODES);
    int*   col    = (int*)  alloc(sizeof(int) * N_EDGES);
    int*   bsum   = (int*)  alloc(sizeof(int) * 512);
    int*   boff   = (int*)  alloc(sizeof(int) * 512);
    unsigned short* w0n = (unsigned short*)alloc(sizeof(unsigned short) * IN_C * HID_C);
    unsigned short* w1n = (unsigned short*)alloc(sizeof(unsigned short) * OUT_CP * HID_C);
    float* b0n = (float*)alloc(sizeof(float) * HID_C);
    float* b1n = (float*)alloc(sizeof(float) * OUT_C);
    unsigned short* h1 = (unsigned short*)alloc(sizeof(unsigned short) * (size_t)N_NODES * HID_C);
    unsigned short* h2 = (unsigned short*)alloc(sizeof(unsigned short) * (size_t)N_NODES * HID_C);
    float* p2 = (float*)h1;  // h1 dead after k_agg1; 16 MB fits inside h1's 25.6 MB

    k_detect<<<1, 64, 0, stream>>>((const unsigned int*)x, ei, flags);
    hipMemsetAsync(w1n, 0, sizeof(unsigned short) * OUT_CP * HID_C, stream);  // zero pad rows 40..47
    k_norm_w<<<(NW_TOTAL + 255) / 256, 256, 0, stream>>>(W0, W1, b0, b1, flags, w0n, w1n, b0n, b1n);

    hipMemsetAsync(cnt, 0, sizeof(int) * N_NODES, stream);
    k_count<<<(N_EDGES + 255) / 256, 256, 0, stream>>>(ei, flags, cnt);
    k_scan_a<<<NB_SCAN, 256, 0, stream>>>(cnt, bsum);
    k_scan_b<<<1, 512, 0, stream>>>(bsum, boff);
    k_scan_c<<<NB_SCAN, 256, 0, stream>>>(cnt, boff, rowptr, cnt, dinv);
    k_fill<<<(N_EDGES + 255) / 256, 256, 0, stream>>>(ei, flags, cnt, col);

    k_gemm1<<<(N_NODES / 16 + 3) / 4, 256, 0, stream>>>(x, w0n, flags, h1);
    k_agg1<<<(N_NODES + 3) / 4, 256, 0, stream>>>(rowptr, col, dinv,
                                                  (const unsigned int*)h1, b0n,
                                                  (unsigned int*)h2);
    k_gemm2<<<(N_NODES / 16 + 3) / 4, 256, 0, stream>>>(h2, w1n, p2);
    k_agg2<<<(N_NODES + 3) / 4, 256, 0, stream>>>(rowptr, col, dinv, p2, b1n, flags, d_out);
}

// Round 5
// 713.388 us; speedup vs baseline: 1.4365x; 1.0690x over previous
//
#include <hip/hip_runtime.h>
#include <hip/hip_bf16.h>
#include <cstddef>

#define N_NODES 100000
#define N_EDGES 1600000
#define IN_C 512
#define HID_C 128
#define OUT_C 40
#define OUT_CP 48   // padded col count for MFMA (3 x 16)
#define NB_SCAN 391  // ceil((N_NODES+1)/256)
#define BK 128       // gemm1 K-slice in LDS
#define PADK 136     // padded LDS row stride (shorts): 68 dwords -> conflict-free

typedef short bf16x8 __attribute__((ext_vector_type(8)));
typedef float f32x4 __attribute__((ext_vector_type(4)));

__device__ __forceinline__ float bf2f(unsigned short u) {
    union { unsigned int i; float f; } v; v.i = ((unsigned int)u) << 16; return v.f;
}
__device__ __forceinline__ float bf2f_lo(unsigned int u) {
    union { unsigned int i; float f; } v; v.i = u << 16; return v.f;
}
__device__ __forceinline__ float bf2f_hi(unsigned int u) {
    union { unsigned int i; float f; } v; v.i = u & 0xFFFF0000u; return v.f;
}
__device__ __forceinline__ unsigned short f2bf(float f) {
    union { float f; unsigned int i; } v; v.f = f;
    unsigned int x = v.i;
    return (unsigned short)((x + 0x7FFFu + ((x >> 16) & 1u)) >> 16);  // RNE
}

// ---- dtype detection -------------------------------------------------------
__global__ void k_detect(const unsigned int* __restrict__ xbits,
                         const int* __restrict__ ei32, int* __restrict__ flags) {
    if (threadIdx.x == 0 && blockIdx.x == 0) {
        int inrange = 0;
        for (int i = 0; i < 64; i++) {
            unsigned int b = xbits[i * 33 + 1];
            int e = (int)((b >> 23) & 0xFFu);
            if (e >= 90 && e <= 160) inrange++;
        }
        flags[0] = (inrange >= 32) ? 0 : 1;
        int zeros = 0;
        for (int i = 0; i < 8; i++) if (ei32[2 * i + 1] == 0) zeros++;
        flags[1] = (zeros == 8) ? 1 : 0;
    }
}

__device__ __forceinline__ int load_src(const int* ei, int mi, int e) {
    return mi ? ei[2 * e] : ei[e];
}
__device__ __forceinline__ int load_dst(const int* ei, int mi, int e) {
    return mi ? ei[2 * (N_EDGES + e)] : ei[N_EDGES + e];
}

// ---- weight/bias normalization ---------------------------------------------
#define NW_TOTAL (IN_C * HID_C + HID_C * OUT_C + HID_C + OUT_C)
__global__ void k_norm_w(const void* __restrict__ W0, const void* __restrict__ W1,
                         const void* __restrict__ b0, const void* __restrict__ b1,
                         const int* __restrict__ flags,
                         unsigned short* __restrict__ w0n, unsigned short* __restrict__ w1n,
                         float* __restrict__ b0n, float* __restrict__ b1n) {
    int mf = flags[0];
    int i = blockIdx.x * 256 + threadIdx.x;
    if (i >= NW_TOTAL) return;
    if (i < IN_C * HID_C) {
        w0n[i] = mf ? ((const unsigned short*)W0)[i] : f2bf(((const float*)W0)[i]);
    } else if (i < IN_C * HID_C + HID_C * OUT_C) {
        int j = i - IN_C * HID_C;
        w1n[j] = mf ? ((const unsigned short*)W1)[j] : f2bf(((const float*)W1)[j]);
    } else if (i < IN_C * HID_C + HID_C * OUT_C + HID_C) {
        int j = i - IN_C * HID_C - HID_C * OUT_C;
        b0n[j] = mf ? bf2f(((const unsigned short*)b0)[j]) : ((const float*)b0)[j];
    } else {
        int j = i - IN_C * HID_C - HID_C * OUT_C - HID_C;
        b1n[j] = mf ? bf2f(((const unsigned short*)b1)[j]) : ((const float*)b1)[j];
    }
}

// ---- CSR build -------------------------------------------------------------

__global__ void k_count(const int* __restrict__ ei, const int* __restrict__ flags,
                        int* __restrict__ cnt) {
    int e = blockIdx.x * 256 + threadIdx.x;
    if (e < N_EDGES) atomicAdd(&cnt[load_dst(ei, flags[1], e)], 1);
}

__global__ void k_scan_a(const int* __restrict__ cnt, int* __restrict__ bsum) {
    __shared__ int sm[256];
    int i = blockIdx.x * 256 + threadIdx.x;
    int v = (i < N_NODES) ? cnt[i] : 0;
    sm[threadIdx.x] = v; __syncthreads();
    for (int s = 128; s > 0; s >>= 1) {
        if (threadIdx.x < s) sm[threadIdx.x] += sm[threadIdx.x + s];
        __syncthreads();
    }
    if (threadIdx.x == 0) bsum[blockIdx.x] = sm[0];
}

__global__ void k_scan_b(const int* __restrict__ bsum, int* __restrict__ boff) {
    __shared__ int sm[512];
    int t = threadIdx.x;
    int v = (t < NB_SCAN) ? bsum[t] : 0;
    sm[t] = v; __syncthreads();
    for (int off = 1; off < 512; off <<= 1) {
        int add = (t >= off) ? sm[t - off] : 0;
        __syncthreads();
        sm[t] += add;
        __syncthreads();
    }
    boff[t] = sm[t] - v;  // exclusive
}

__global__ void k_scan_c(const int* cnt, const int* __restrict__ boff,
                         int* __restrict__ rowptr, int* cursor, float* __restrict__ dinv) {
    __shared__ int sm[256];
    int t = threadIdx.x;
    int i = blockIdx.x * 256 + t;
    int v = (i < N_NODES) ? cnt[i] : 0;
    sm[t] = v; __syncthreads();
    for (int off = 1; off < 256; off <<= 1) {
        int add = (t >= off) ? sm[t - off] : 0;
        __syncthreads();
        sm[t] += add;
        __syncthreads();
    }
    int p = boff[blockIdx.x] + sm[t] - v;
    if (i < N_NODES) {
        rowptr[i] = p;
        cursor[i] = p;
        float d = (float)v;
        if (d < 1.0f) d = 1.0f;
        dinv[i] = rsqrtf(d);
    } else if (i == N_NODES) {
        rowptr[N_NODES] = p;
    }
}

__global__ void k_fill(const int* __restrict__ ei, const int* __restrict__ flags,
                       int* cursor, int* __restrict__ col) {
    int e = blockIdx.x * 256 + threadIdx.x;
    if (e < N_EDGES) {
        int mi = flags[1];
        int d = load_dst(ei, mi, e);
        int p = atomicAdd(&cursor[d], 1);
        col[p] = load_src(ei, mi, e);
    }
}

// ---- GEMM1 v2: H1[N,128] = x[N,512] @ W0[128,512]^T ------------------------
// Block: 256 thr (4 waves) -> 128 nodes x 128 ch. W0 staged in LDS per BK=128
// slice (padded stride 136 shorts -> conflict-free ds_read_b128). Each wave:
// 2 m-frags (32 nodes), B frags reused across both -> 16 MFMA per k-step.
template <int MF>
__device__ __forceinline__ void gemm1_body(const void* __restrict__ x,
                                           const unsigned short* __restrict__ w0n,
                                           unsigned short* __restrict__ h1,
                                           unsigned short* __restrict__ Bl,
                                           int node0, int t) {
    int w = t >> 6;
    int lane = t & 63;
    int r16 = lane & 15;
    int quad = lane >> 4;

    f32x4 acc[2][8];
#pragma unroll
    for (int m = 0; m < 2; m++)
#pragma unroll
        for (int c = 0; c < 8; c++) acc[m][c] = (f32x4){0.f, 0.f, 0.f, 0.f};

    int row0 = node0 + w * 32 + r16;
    int row1 = row0 + 16;
    int r0c = row0 < N_NODES ? row0 : N_NODES - 1;
    int r1c = row1 < N_NODES ? row1 : N_NODES - 1;
    const float* a0f = (const float*)x + (size_t)r0c * IN_C + quad * 8;
    const float* a1f = (const float*)x + (size_t)r1c * IN_C + quad * 8;
    const unsigned short* a0h = (const unsigned short*)x + (size_t)r0c * IN_C + quad * 8;
    const unsigned short* a1h = (const unsigned short*)x + (size_t)r1c * IN_C + quad * 8;

    int ch = t >> 1, half = t & 1;  // B-fill mapping: 2 threads per channel row
    const unsigned short* gfill = w0n + (size_t)ch * IN_C + half * 64;
    unsigned short* lfill = Bl + ch * PADK + half * 64;

    for (int s = 0; s < 4; s++) {
        int ks0 = s * BK;
        __syncthreads();
#pragma unroll
        for (int i = 0; i < 8; i++) {
            *reinterpret_cast<bf16x8*>(lfill + i * 8) =
                *reinterpret_cast<const bf16x8*>(gfill + ks0 + i * 8);
        }
        __syncthreads();
#pragma unroll
        for (int kk = 0; kk < BK; kk += 32) {
            int k0 = ks0 + kk;
            bf16x8 a0, a1;
            if (MF) {
                a0 = *reinterpret_cast<const bf16x8*>(a0h + k0);
                a1 = *reinterpret_cast<const bf16x8*>(a1h + k0);
            } else {
                float4 f0 = *reinterpret_cast<const float4*>(a0f + k0);
                float4 f1 = *reinterpret_cast<const float4*>(a0f + k0 + 4);
                float4 g0 = *reinterpret_cast<const float4*>(a1f + k0);
                float4 g1 = *reinterpret_cast<const float4*>(a1f + k0 + 4);
                a0 = (bf16x8){(short)f2bf(f0.x), (short)f2bf(f0.y), (short)f2bf(f0.z), (short)f2bf(f0.w),
                              (short)f2bf(f1.x), (short)f2bf(f1.y), (short)f2bf(f1.z), (short)f2bf(f1.w)};
                a1 = (bf16x8){(short)f2bf(g0.x), (short)f2bf(g0.y), (short)f2bf(g0.z), (short)f2bf(g0.w),
                              (short)f2bf(g1.x), (short)f2bf(g1.y), (short)f2bf(g1.z), (short)f2bf(g1.w)};
            }
            const unsigned short* bbase = Bl + r16 * PADK + kk + quad * 8;
#pragma unroll
            for (int ct = 0; ct < 8; ct++) {
                bf16x8 b = *reinterpret_cast<const bf16x8*>(bbase + ct * 16 * PADK);
                acc[0][ct] = __builtin_amdgcn_mfma_f32_16x16x32_bf16(a0, b, acc[0][ct], 0, 0, 0);
                acc[1][ct] = __builtin_amdgcn_mfma_f32_16x16x32_bf16(a1, b, acc[1][ct], 0, 0, 0);
            }
        }
    }

#pragma unroll
    for (int m = 0; m < 2; m++) {
#pragma unroll
        for (int ct = 0; ct < 8; ct++) {
#pragma unroll
            for (int r = 0; r < 4; r++) {
                int row = node0 + w * 32 + m * 16 + quad * 4 + r;
                if (row < N_NODES)
                    h1[(size_t)row * HID_C + ct * 16 + r16] = f2bf(acc[m][ct][r]);
            }
        }
    }
}

__global__ __launch_bounds__(256, 3) void k_gemm1(const void* __restrict__ x,
                                                  const unsigned short* __restrict__ w0n,
                                                  const int* __restrict__ flags,
                                                  unsigned short* __restrict__ h1) {
    __shared__ unsigned short Bl[HID_C * PADK];  // 34,816 B
    int node0 = blockIdx.x * 128;
    int t = threadIdx.x;
    if (flags[0]) gemm1_body<1>(x, w0n, h1, Bl, node0, t);
    else          gemm1_body<0>(x, w0n, h1, Bl, node0, t);
}

// ---- Agg layer 1 (+bias+relu): one wave per node, uint(2xbf16)/lane, x8 ILP
__global__ __launch_bounds__(256) void k_agg1(const int* __restrict__ rowptr,
                                              const int* __restrict__ col,
                                              const float* __restrict__ dinv,
                                              const unsigned int* __restrict__ h1v,
                                              const float* __restrict__ b0n,
                                              unsigned int* __restrict__ h2v) {
    int w = threadIdx.x >> 6;
    int lane = threadIdx.x & 63;
    int d = blockIdx.x * 4 + w;
    if (d >= N_NODES) return;
    int beg = rowptr[d], end = rowptr[d + 1];
    float a0 = 0.f, a1 = 0.f;
    int j = beg;
    for (; j + 8 <= end; j += 8) {
        int s[8];
        float wj[8];
        unsigned int r[8];
#pragma unroll
        for (int q = 0; q < 8; q++) s[q] = col[j + q];
#pragma unroll
        for (int q = 0; q < 8; q++) wj[q] = dinv[s[q]];
#pragma unroll
        for (int q = 0; q < 8; q++) r[q] = h1v[(size_t)s[q] * 64 + lane];
#pragma unroll
        for (int q = 0; q < 8; q++) {
            a0 += wj[q] * bf2f_lo(r[q]);
            a1 += wj[q] * bf2f_hi(r[q]);
        }
    }
    for (; j < end; j++) {
        int s = col[j];
        float wj = dinv[s];
        unsigned int r = h1v[(size_t)s * 64 + lane];
        a0 += wj * bf2f_lo(r);
        a1 += wj * bf2f_hi(r);
    }
    float dv = dinv[d];
    float o0 = a0 * dv + b0n[2 * lane];
    float o1 = a1 * dv + b0n[2 * lane + 1];
    o0 = o0 > 0.f ? o0 : 0.f;
    o1 = o1 > 0.f ? o1 : 0.f;
    h2v[(size_t)d * 64 + lane] = (unsigned int)f2bf(o0) | ((unsigned int)f2bf(o1) << 16);
}

// ---- GEMM2 (MFMA): P2[N,40] = H2[N,128] @ W1p[48,128]^T --------------------
__global__ __launch_bounds__(256) void k_gemm2(const unsigned short* __restrict__ h2,
                                               const unsigned short* __restrict__ w1p,
                                               float* __restrict__ p2) {
    int wave = (blockIdx.x * 256 + (int)threadIdx.x) >> 6;
    if (wave >= N_NODES / 16) return;
    int lane = threadIdx.x & 63;
    int r16 = lane & 15;
    int quad = lane >> 4;
    int node_base = wave * 16;

    f32x4 acc[3];
#pragma unroll
    for (int c = 0; c < 3; c++) acc[c] = (f32x4){0.f, 0.f, 0.f, 0.f};

    const unsigned short* arow = h2 + (size_t)(node_base + r16) * HID_C + quad * 8;
    const unsigned short* brow = w1p + (size_t)r16 * HID_C + quad * 8;

#pragma unroll
    for (int k0 = 0; k0 < HID_C; k0 += 32) {
        bf16x8 a = *reinterpret_cast<const bf16x8*>(arow + k0);
#pragma unroll
        for (int ct = 0; ct < 3; ct++) {
            bf16x8 b = *reinterpret_cast<const bf16x8*>(brow + (size_t)ct * 16 * HID_C + k0);
            acc[ct] = __builtin_amdgcn_mfma_f32_16x16x32_bf16(a, b, acc[ct], 0, 0, 0);
        }
    }

#pragma unroll
    for (int ct = 0; ct < 3; ct++) {
        int chan = ct * 16 + r16;
        if (chan < OUT_C) {
#pragma unroll
            for (int r = 0; r < 4; r++) {
                p2[(size_t)(node_base + quad * 4 + r) * OUT_C + chan] = acc[ct][r];
            }
        }
    }
}

// ---- Agg layer 2 (+bias): one wave per node, lanes 0..39, x8 ILP -----------
__global__ __launch_bounds__(256) void k_agg2(const int* __restrict__ rowptr,
                                              const int* __restrict__ col,
                                              const float* __restrict__ dinv,
                                              const float* __restrict__ p2,
                                              const float* __restrict__ b1n,
                                              const int* __restrict__ flags,
                                              void* __restrict__ out) {
    int w = threadIdx.x >> 6;
    int lane = threadIdx.x & 63;
    int d = blockIdx.x * 4 + w;
    if (d >= N_NODES || lane >= OUT_C) return;
    int beg = rowptr[d], end = rowptr[d + 1];
    float acc = 0.f;
    int j = beg;
    for (; j + 8 <= end; j += 8) {
        int s[8];
        float wj[8], r[8];
#pragma unroll
        for (int q = 0; q < 8; q++) s[q] = col[j + q];
#pragma unroll
        for (int q = 0; q < 8; q++) wj[q] = dinv[s[q]];
#pragma unroll
        for (int q = 0; q < 8; q++) r[q] = p2[(size_t)s[q] * OUT_C + lane];
#pragma unroll
        for (int q = 0; q < 8; q++) acc += wj[q] * r[q];
    }
    for (; j < end; j++) {
        int s = col[j];
        acc += dinv[s] * p2[(size_t)s * OUT_C + lane];
    }
    float v = acc * dinv[d] + b1n[lane];
    size_t idx = (size_t)d * OUT_C + lane;
    if (flags[0]) ((unsigned short*)out)[idx] = f2bf(v);
    else          ((float*)out)[idx] = v;
}

extern "C" void kernel_launch(void* const* d_in, const int* in_sizes, int n_in,
                              void* d_out, int out_size, void* d_ws, size_t ws_size,
                              hipStream_t stream) {
    const void* x  = d_in[0];
    const int* ei  = (const int*)d_in[1];
    const void* W0 = d_in[2];
    const void* b0 = d_in[3];
    const void* W1 = d_in[4];
    const void* b1 = d_in[5];

    char* ws = (char*)d_ws;
    size_t off = 0;
    auto alloc = [&](size_t bytes) {
        char* p = ws + off;
        off += (bytes + 511) & ~(size_t)511;
        return p;
    };
    // Total footprint ~59 MB.
    int*   flags  = (int*)  alloc(sizeof(int) * 2);
    int*   cnt    = (int*)  alloc(sizeof(int) * N_NODES);        // reused as cursor
    int*   rowptr = (int*)  alloc(sizeof(int) * (N_NODES + 1));
    float* dinv   = (float*)alloc(sizeof(float) * N_NODES);
    int*   col    = (int*)  alloc(sizeof(int) * N_EDGES);
    int*   bsum   = (int*)  alloc(sizeof(int) * 512);
    int*   boff   = (int*)  alloc(sizeof(int) * 512);
    unsigned short* w0n = (unsigned short*)alloc(sizeof(unsigned short) * IN_C * HID_C);
    unsigned short* w1n = (unsigned short*)alloc(sizeof(unsigned short) * OUT_CP * HID_C);
    float* b0n = (float*)alloc(sizeof(float) * HID_C);
    float* b1n = (float*)alloc(sizeof(float) * OUT_C);
    unsigned short* h1 = (unsigned short*)alloc(sizeof(unsigned short) * (size_t)N_NODES * HID_C);
    unsigned short* h2 = (unsigned short*)alloc(sizeof(unsigned short) * (size_t)N_NODES * HID_C);
    float* p2 = (float*)h1;  // h1 dead after k_agg1; 16 MB fits inside h1's 25.6 MB

    k_detect<<<1, 64, 0, stream>>>((const unsigned int*)x, ei, flags);
    hipMemsetAsync(w1n, 0, sizeof(unsigned short) * OUT_CP * HID_C, stream);
    k_norm_w<<<(NW_TOTAL + 255) / 256, 256, 0, stream>>>(W0, W1, b0, b1, flags, w0n, w1n, b0n, b1n);

    hipMemsetAsync(cnt, 0, sizeof(int) * N_NODES, stream);
    k_count<<<(N_EDGES + 255) / 256, 256, 0, stream>>>(ei, flags, cnt);
    k_scan_a<<<NB_SCAN, 256, 0, stream>>>(cnt, bsum);
    k_scan_b<<<1, 512, 0, stream>>>(bsum, boff);
    k_scan_c<<<NB_SCAN, 256, 0, stream>>>(cnt, boff, rowptr, cnt, dinv);
    k_fill<<<(N_EDGES + 255) / 256, 256, 0, stream>>>(ei, flags, cnt, col);

    k_gemm1<<<(N_NODES + 127) / 128, 256, 0, stream>>>(x, w0n, flags, h1);
    k_agg1<<<(N_NODES + 3) / 4, 256, 0, stream>>>(rowptr, col, dinv,
                                                  (const unsigned int*)h1, b0n,
                                                  (unsigned int*)h2);
    k_gemm2<<<(N_NODES / 16 + 3) / 4, 256, 0, stream>>>(h2, w1n, p2);
    k_agg2<<<(N_NODES + 3) / 4, 256, 0, stream>>>(rowptr, col, dinv, p2, b1n, flags, d_out);
}

// Round 6
// 568.235 us; speedup vs baseline: 1.8034x; 1.2554x over previous
//
#include <hip/hip_runtime.h>
#include <hip/hip_bf16.h>
#include <cstddef>

#define N_NODES 100000
#define N_EDGES 1600000
#define IN_C 512
#define HID_C 128
#define OUT_C 40
#define OUT_CP 48   // padded col count for MFMA (3 x 16)
#define BK 128      // gemm1 K-slice in LDS
#define PADK 136    // padded LDS row stride (shorts)
#define EPB 8000    // edges per partition block
#define NPART 200   // ceil(N_EDGES / EPB)
#define NBKT 196    // buckets of 512 nodes (dst >> 9); 99999>>9 = 195
#define BSHIFT 9

typedef short bf16x8 __attribute__((ext_vector_type(8)));
typedef float f32x4 __attribute__((ext_vector_type(4)));

__device__ __forceinline__ float bf2f(unsigned short u) {
    union { unsigned int i; float f; } v; v.i = ((unsigned int)u) << 16; return v.f;
}
__device__ __forceinline__ float bf2f_lo(unsigned int u) {
    union { unsigned int i; float f; } v; v.i = u << 16; return v.f;
}
__device__ __forceinline__ float bf2f_hi(unsigned int u) {
    union { unsigned int i; float f; } v; v.i = u & 0xFFFF0000u; return v.f;
}
__device__ __forceinline__ unsigned short f2bf(float f) {
    union { float f; unsigned int i; } v; v.f = f;
    unsigned int x = v.i;
    return (unsigned short)((x + 0x7FFFu + ((x >> 16) & 1u)) >> 16);  // RNE
}

// ---- dtype detection -------------------------------------------------------
__global__ void k_detect(const unsigned int* __restrict__ xbits,
                         const int* __restrict__ ei32, int* __restrict__ flags) {
    if (threadIdx.x == 0 && blockIdx.x == 0) {
        int inrange = 0;
        for (int i = 0; i < 64; i++) {
            unsigned int b = xbits[i * 33 + 1];
            int e = (int)((b >> 23) & 0xFFu);
            if (e >= 90 && e <= 160) inrange++;
        }
        flags[0] = (inrange >= 32) ? 0 : 1;
        int zeros = 0;
        for (int i = 0; i < 8; i++) if (ei32[2 * i + 1] == 0) zeros++;
        flags[1] = (zeros == 8) ? 1 : 0;
    }
}

__device__ __forceinline__ int load_src(const int* ei, int mi, int e) {
    return mi ? ei[2 * e] : ei[e];
}
__device__ __forceinline__ int load_dst(const int* ei, int mi, int e) {
    return mi ? ei[2 * (N_EDGES + e)] : ei[N_EDGES + e];
}

// ---- weight/bias normalization ---------------------------------------------
#define NW_TOTAL (IN_C * HID_C + HID_C * OUT_C + HID_C + OUT_C)
__global__ void k_norm_w(const void* __restrict__ W0, const void* __restrict__ W1,
                         const void* __restrict__ b0, const void* __restrict__ b1,
                         const int* __restrict__ flags,
                         unsigned short* __restrict__ w0n, unsigned short* __restrict__ w1n,
                         float* __restrict__ b0n, float* __restrict__ b1n) {
    int mf = flags[0];
    int i = blockIdx.x * 256 + threadIdx.x;
    if (i >= NW_TOTAL) return;
    if (i < IN_C * HID_C) {
        w0n[i] = mf ? ((const unsigned short*)W0)[i] : f2bf(((const float*)W0)[i]);
    } else if (i < IN_C * HID_C + HID_C * OUT_C) {
        int j = i - IN_C * HID_C;
        w1n[j] = mf ? ((const unsigned short*)W1)[j] : f2bf(((const float*)W1)[j]);
    } else if (i < IN_C * HID_C + HID_C * OUT_C + HID_C) {
        int j = i - IN_C * HID_C - HID_C * OUT_C;
        b0n[j] = mf ? bf2f(((const unsigned short*)b0)[j]) : ((const float*)b0)[j];
    } else {
        int j = i - IN_C * HID_C - HID_C * OUT_C - HID_C;
        b1n[j] = mf ? bf2f(((const unsigned short*)b1)[j]) : ((const float*)b1)[j];
    }
}

// ---- Bucketed CSR build ----------------------------------------------------
// P1: per-block LDS histogram over 196 dst-buckets + global reservation.
__global__ __launch_bounds__(256) void k_part1(const int* __restrict__ ei,
                                               const int* __restrict__ flags,
                                               int* __restrict__ bcnt,
                                               int* __restrict__ block_off) {
    __shared__ int h[NBKT];
    int t = threadIdx.x;
    for (int i = t; i < NBKT; i += 256) h[i] = 0;
    __syncthreads();
    int mi = flags[1];
    int base = blockIdx.x * EPB;
    for (int j = t; j < EPB; j += 256) {
        int e = base + j;
        if (e < N_EDGES) atomicAdd(&h[load_dst(ei, mi, e) >> BSHIFT], 1);
    }
    __syncthreads();
    for (int i = t; i < NBKT; i += 256)
        block_off[blockIdx.x * NBKT + i] = atomicAdd(&bcnt[i], h[i]);
}

// P2: exclusive scan of bucket counts -> bbase[0..NBKT] (bbase[NBKT] = N_EDGES).
__global__ void k_scan_bkt(const int* __restrict__ bcnt, int* __restrict__ bbase) {
    __shared__ int sm[256];
    int t = threadIdx.x;
    int v = (t < NBKT) ? bcnt[t] : 0;
    sm[t] = v; __syncthreads();
    for (int off = 1; off < 256; off <<= 1) {
        int a = (t >= off) ? sm[t - off] : 0;
        __syncthreads();
        sm[t] += a;
        __syncthreads();
    }
    if (t < NBKT) bbase[t] = sm[t] - v;
    if (t == NBKT - 1) bbase[NBKT] = sm[t];
}

// P3: scatter packed (src<<9 | dst&511) into per-block-contiguous bucket chunks.
__global__ __launch_bounds__(256) void k_part2(const int* __restrict__ ei,
                                               const int* __restrict__ flags,
                                               const int* __restrict__ bbase,
                                               const int* __restrict__ block_off,
                                               unsigned int* __restrict__ bedges) {
    __shared__ int cur[NBKT];
    int t = threadIdx.x;
    for (int i = t; i < NBKT; i += 256)
        cur[i] = bbase[i] + block_off[blockIdx.x * NBKT + i];
    __syncthreads();
    int mi = flags[1];
    int base = blockIdx.x * EPB;
    for (int j = t; j < EPB; j += 256) {
        int e = base + j;
        if (e < N_EDGES) {
            int d = load_dst(ei, mi, e);
            int s = load_src(ei, mi, e);
            int p = atomicAdd(&cur[d >> BSHIFT], 1);
            bedges[p] = ((unsigned int)s << BSHIFT) | (unsigned int)(d & 511);
        }
    }
}

// P4: one block per bucket. LDS count -> LDS scan -> rowptr/dinv, then scatter
// col into the bucket's exclusive ~32 KB window (single-XCD L2, full-line wb).
__global__ __launch_bounds__(512) void k_bucket_csr(const unsigned int* __restrict__ bedges,
                                                    const int* __restrict__ bbase,
                                                    int* __restrict__ rowptr,
                                                    float* __restrict__ dinv,
                                                    int* __restrict__ col) {
    __shared__ int cnt[512];
    __shared__ int cur[512];
    int b = blockIdx.x, t = threadIdx.x;
    int ebeg = bbase[b], eend = bbase[b + 1];
    cnt[t] = 0;
    __syncthreads();
    for (int j = ebeg + t; j < eend; j += 512)
        atomicAdd(&cnt[bedges[j] & 511], 1);
    __syncthreads();
    int v = cnt[t];
    cur[t] = v; __syncthreads();
    for (int off = 1; off < 512; off <<= 1) {
        int a = (t >= off) ? cur[t - off] : 0;
        __syncthreads();
        cur[t] += a;
        __syncthreads();
    }
    int excl = cur[t] - v;
    int node = b * 512 + t;
    if (node < N_NODES) {
        rowptr[node] = ebeg + excl;
        float dd = (float)v; if (dd < 1.f) dd = 1.f;
        dinv[node] = rsqrtf(dd);
    } else if (node == N_NODES) {
        rowptr[N_NODES] = ebeg + excl;  // == N_EDGES (no dst >= N_NODES exists)
    }
    __syncthreads();
    cur[t] = ebeg + excl;
    __syncthreads();
    for (int j = ebeg + t; j < eend; j += 512) {
        unsigned int pk = bedges[j];
        int p = atomicAdd(&cur[pk & 511], 1);
        col[p] = (int)(pk >> BSHIFT);
    }
}

// ---- GEMM1 v2: H1[N,128] = x[N,512] @ W0[128,512]^T ------------------------
template <int MF>
__device__ __forceinline__ void gemm1_body(const void* __restrict__ x,
                                           const unsigned short* __restrict__ w0n,
                                           unsigned short* __restrict__ h1,
                                           unsigned short* __restrict__ Bl,
                                           int node0, int t) {
    int w = t >> 6;
    int lane = t & 63;
    int r16 = lane & 15;
    int quad = lane >> 4;

    f32x4 acc[2][8];
#pragma unroll
    for (int m = 0; m < 2; m++)
#pragma unroll
        for (int c = 0; c < 8; c++) acc[m][c] = (f32x4){0.f, 0.f, 0.f, 0.f};

    int row0 = node0 + w * 32 + r16;
    int row1 = row0 + 16;
    int r0c = row0 < N_NODES ? row0 : N_NODES - 1;
    int r1c = row1 < N_NODES ? row1 : N_NODES - 1;
    const float* a0f = (const float*)x + (size_t)r0c * IN_C + quad * 8;
    const float* a1f = (const float*)x + (size_t)r1c * IN_C + quad * 8;
    const unsigned short* a0h = (const unsigned short*)x + (size_t)r0c * IN_C + quad * 8;
    const unsigned short* a1h = (const unsigned short*)x + (size_t)r1c * IN_C + quad * 8;

    int ch = t >> 1, half = t & 1;
    const unsigned short* gfill = w0n + (size_t)ch * IN_C + half * 64;
    unsigned short* lfill = Bl + ch * PADK + half * 64;

    for (int s = 0; s < 4; s++) {
        int ks0 = s * BK;
        __syncthreads();
#pragma unroll
        for (int i = 0; i < 8; i++) {
            *reinterpret_cast<bf16x8*>(lfill + i * 8) =
                *reinterpret_cast<const bf16x8*>(gfill + ks0 + i * 8);
        }
        __syncthreads();
#pragma unroll
        for (int kk = 0; kk < BK; kk += 32) {
            int k0 = ks0 + kk;
            bf16x8 a0, a1;
            if (MF) {
                a0 = *reinterpret_cast<const bf16x8*>(a0h + k0);
                a1 = *reinterpret_cast<const bf16x8*>(a1h + k0);
            } else {
                float4 f0 = *reinterpret_cast<const float4*>(a0f + k0);
                float4 f1 = *reinterpret_cast<const float4*>(a0f + k0 + 4);
                float4 g0 = *reinterpret_cast<const float4*>(a1f + k0);
                float4 g1 = *reinterpret_cast<const float4*>(a1f + k0 + 4);
                a0 = (bf16x8){(short)f2bf(f0.x), (short)f2bf(f0.y), (short)f2bf(f0.z), (short)f2bf(f0.w),
                              (short)f2bf(f1.x), (short)f2bf(f1.y), (short)f2bf(f1.z), (short)f2bf(f1.w)};
                a1 = (bf16x8){(short)f2bf(g0.x), (short)f2bf(g0.y), (short)f2bf(g0.z), (short)f2bf(g0.w),
                              (short)f2bf(g1.x), (short)f2bf(g1.y), (short)f2bf(g1.z), (short)f2bf(g1.w)};
            }
            const unsigned short* bbase2 = Bl + r16 * PADK + kk + quad * 8;
#pragma unroll
            for (int ct = 0; ct < 8; ct++) {
                bf16x8 b = *reinterpret_cast<const bf16x8*>(bbase2 + ct * 16 * PADK);
                acc[0][ct] = __builtin_amdgcn_mfma_f32_16x16x32_bf16(a0, b, acc[0][ct], 0, 0, 0);
                acc[1][ct] = __builtin_amdgcn_mfma_f32_16x16x32_bf16(a1, b, acc[1][ct], 0, 0, 0);
            }
        }
    }

#pragma unroll
    for (int m = 0; m < 2; m++) {
#pragma unroll
        for (int ct = 0; ct < 8; ct++) {
#pragma unroll
            for (int r = 0; r < 4; r++) {
                int row = node0 + w * 32 + m * 16 + quad * 4 + r;
                if (row < N_NODES)
                    h1[(size_t)row * HID_C + ct * 16 + r16] = f2bf(acc[m][ct][r]);
            }
        }
    }
}

__global__ __launch_bounds__(256, 3) void k_gemm1(const void* __restrict__ x,
                                                  const unsigned short* __restrict__ w0n,
                                                  const int* __restrict__ flags,
                                                  unsigned short* __restrict__ h1) {
    __shared__ unsigned short Bl[HID_C * PADK];
    int node0 = blockIdx.x * 128;
    int t = threadIdx.x;
    if (flags[0]) gemm1_body<1>(x, w0n, h1, Bl, node0, t);
    else          gemm1_body<0>(x, w0n, h1, Bl, node0, t);
}

// ---- Agg layer 1 (+bias+relu): one wave per node, uint(2xbf16)/lane, x8 ILP
__global__ __launch_bounds__(256) void k_agg1(const int* __restrict__ rowptr,
                                              const int* __restrict__ col,
                                              const float* __restrict__ dinv,
                                              const unsigned int* __restrict__ h1v,
                                              const float* __restrict__ b0n,
                                              unsigned int* __restrict__ h2v) {
    int w = threadIdx.x >> 6;
    int lane = threadIdx.x & 63;
    int d = blockIdx.x * 4 + w;
    if (d >= N_NODES) return;
    int beg = rowptr[d], end = rowptr[d + 1];
    float a0 = 0.f, a1 = 0.f;
    int j = beg;
    for (; j + 8 <= end; j += 8) {
        int s[8];
        float wj[8];
        unsigned int r[8];
#pragma unroll
        for (int q = 0; q < 8; q++) s[q] = col[j + q];
#pragma unroll
        for (int q = 0; q < 8; q++) wj[q] = dinv[s[q]];
#pragma unroll
        for (int q = 0; q < 8; q++) r[q] = h1v[(size_t)s[q] * 64 + lane];
#pragma unroll
        for (int q = 0; q < 8; q++) {
            a0 += wj[q] * bf2f_lo(r[q]);
            a1 += wj[q] * bf2f_hi(r[q]);
        }
    }
    for (; j < end; j++) {
        int s = col[j];
        float wj = dinv[s];
        unsigned int r = h1v[(size_t)s * 64 + lane];
        a0 += wj * bf2f_lo(r);
        a1 += wj * bf2f_hi(r);
    }
    float dv = dinv[d];
    float o0 = a0 * dv + b0n[2 * lane];
    float o1 = a1 * dv + b0n[2 * lane + 1];
    o0 = o0 > 0.f ? o0 : 0.f;
    o1 = o1 > 0.f ? o1 : 0.f;
    h2v[(size_t)d * 64 + lane] = (unsigned int)f2bf(o0) | ((unsigned int)f2bf(o1) << 16);
}

// ---- GEMM2 (MFMA): P2[N,40] = H2[N,128] @ W1p[48,128]^T --------------------
__global__ __launch_bounds__(256) void k_gemm2(const unsigned short* __restrict__ h2,
                                               const unsigned short* __restrict__ w1p,
                                               float* __restrict__ p2) {
    int wave = (blockIdx.x * 256 + (int)threadIdx.x) >> 6;
    if (wave >= N_NODES / 16) return;
    int lane = threadIdx.x & 63;
    int r16 = lane & 15;
    int quad = lane >> 4;
    int node_base = wave * 16;

    f32x4 acc[3];
#pragma unroll
    for (int c = 0; c < 3; c++) acc[c] = (f32x4){0.f, 0.f, 0.f, 0.f};

    const unsigned short* arow = h2 + (size_t)(node_base + r16) * HID_C + quad * 8;
    const unsigned short* brow = w1p + (size_t)r16 * HID_C + quad * 8;

#pragma unroll
    for (int k0 = 0; k0 < HID_C; k0 += 32) {
        bf16x8 a = *reinterpret_cast<const bf16x8*>(arow + k0);
#pragma unroll
        for (int ct = 0; ct < 3; ct++) {
            bf16x8 b = *reinterpret_cast<const bf16x8*>(brow + (size_t)ct * 16 * HID_C + k0);
            acc[ct] = __builtin_amdgcn_mfma_f32_16x16x32_bf16(a, b, acc[ct], 0, 0, 0);
        }
    }

#pragma unroll
    for (int ct = 0; ct < 3; ct++) {
        int chan = ct * 16 + r16;
        if (chan < OUT_C) {
#pragma unroll
            for (int r = 0; r < 4; r++) {
                p2[(size_t)(node_base + quad * 4 + r) * OUT_C + chan] = acc[ct][r];
            }
        }
    }
}

// ---- Agg layer 2 (+bias): one wave per node, lanes 0..39, x8 ILP -----------
__global__ __launch_bounds__(256) void k_agg2(const int* __restrict__ rowptr,
                                              const int* __restrict__ col,
                                              const float* __restrict__ dinv,
                                              const float* __restrict__ p2,
                                              const float* __restrict__ b1n,
                                              const int* __restrict__ flags,
                                              void* __restrict__ out) {
    int w = threadIdx.x >> 6;
    int lane = threadIdx.x & 63;
    int d = blockIdx.x * 4 + w;
    if (d >= N_NODES || lane >= OUT_C) return;
    int beg = rowptr[d], end = rowptr[d + 1];
    float acc = 0.f;
    int j = beg;
    for (; j + 8 <= end; j += 8) {
        int s[8];
        float wj[8], r[8];
#pragma unroll
        for (int q = 0; q < 8; q++) s[q] = col[j + q];
#pragma unroll
        for (int q = 0; q < 8; q++) wj[q] = dinv[s[q]];
#pragma unroll
        for (int q = 0; q < 8; q++) r[q] = p2[(size_t)s[q] * OUT_C + lane];
#pragma unroll
        for (int q = 0; q < 8; q++) acc += wj[q] * r[q];
    }
    for (; j < end; j++) {
        int s = col[j];
        acc += dinv[s] * p2[(size_t)s * OUT_C + lane];
    }
    float v = acc * dinv[d] + b1n[lane];
    size_t idx = (size_t)d * OUT_C + lane;
    if (flags[0]) ((unsigned short*)out)[idx] = f2bf(v);
    else          ((float*)out)[idx] = v;
}

extern "C" void kernel_launch(void* const* d_in, const int* in_sizes, int n_in,
                              void* d_out, int out_size, void* d_ws, size_t ws_size,
                              hipStream_t stream) {
    const void* x  = d_in[0];
    const int* ei  = (const int*)d_in[1];
    const void* W0 = d_in[2];
    const void* b0 = d_in[3];
    const void* W1 = d_in[4];
    const void* b1 = d_in[5];

    char* ws = (char*)d_ws;
    size_t off = 0;
    auto alloc = [&](size_t bytes) {
        char* p = ws + off;
        off += (bytes + 511) & ~(size_t)511;
        return p;
    };
    // Total footprint ~66 MB.
    int*   flags   = (int*)  alloc(sizeof(int) * 2);
    int*   rowptr  = (int*)  alloc(sizeof(int) * (N_NODES + 1));
    float* dinv    = (float*)alloc(sizeof(float) * N_NODES);
    int*   col     = (int*)  alloc(sizeof(int) * N_EDGES);
    int*   bcnt    = (int*)  alloc(sizeof(int) * NBKT);
    int*   bbase   = (int*)  alloc(sizeof(int) * (NBKT + 1));
    int*   bloff   = (int*)  alloc(sizeof(int) * NPART * NBKT);
    unsigned int* bedges = (unsigned int*)alloc(sizeof(unsigned int) * N_EDGES);
    unsigned short* w0n = (unsigned short*)alloc(sizeof(unsigned short) * IN_C * HID_C);
    unsigned short* w1n = (unsigned short*)alloc(sizeof(unsigned short) * OUT_CP * HID_C);
    float* b0n = (float*)alloc(sizeof(float) * HID_C);
    float* b1n = (float*)alloc(sizeof(float) * OUT_C);
    unsigned short* h1 = (unsigned short*)alloc(sizeof(unsigned short) * (size_t)N_NODES * HID_C);
    unsigned short* h2 = (unsigned short*)alloc(sizeof(unsigned short) * (size_t)N_NODES * HID_C);
    float* p2 = (float*)h1;  // h1 dead after k_agg1; 16 MB fits inside h1's 25.6 MB

    k_detect<<<1, 64, 0, stream>>>((const unsigned int*)x, ei, flags);
    hipMemsetAsync(w1n, 0, sizeof(unsigned short) * OUT_CP * HID_C, stream);
    k_norm_w<<<(NW_TOTAL + 255) / 256, 256, 0, stream>>>(W0, W1, b0, b1, flags, w0n, w1n, b0n, b1n);

    hipMemsetAsync(bcnt, 0, sizeof(int) * NBKT, stream);
    k_part1<<<NPART, 256, 0, stream>>>(ei, flags, bcnt, bloff);
    k_scan_bkt<<<1, 256, 0, stream>>>(bcnt, bbase);
    k_part2<<<NPART, 256, 0, stream>>>(ei, flags, bbase, bloff, bedges);
    k_bucket_csr<<<NBKT, 512, 0, stream>>>(bedges, bbase, rowptr, dinv, col);

    k_gemm1<<<(N_NODES + 127) / 128, 256, 0, stream>>>(x, w0n, flags, h1);
    k_agg1<<<(N_NODES + 3) / 4, 256, 0, stream>>>(rowptr, col, dinv,
                                                  (const unsigned int*)h1, b0n,
                                                  (unsigned int*)h2);
    k_gemm2<<<(N_NODES / 16 + 3) / 4, 256, 0, stream>>>(h2, w1n, p2);
    k_agg2<<<(N_NODES + 3) / 4, 256, 0, stream>>>(rowptr, col, dinv, p2, b1n, flags, d_out);
}